// Round 8
// baseline (305.687 us; speedup 1.0000x reference)
//
#include <hip/hip_runtime.h>
#include <hip/hip_cooperative_groups.h>
#include <stdint.h>

namespace cg = cooperative_groups;

#define N_BATCH 32
#define B_OBJ   36
#define D_DIM   2048
#define Q_DIM   1024

typedef __bf16 bf16x8 __attribute__((ext_vector_type(8)));
typedef float  f32x4  __attribute__((ext_vector_type(4)));

__device__ __forceinline__ uint16_t f2bf(float f) {
    uint32_t u = __builtin_bit_cast(uint32_t, f);
    uint32_t r = (u + 0x7FFFu + ((u >> 16) & 1u)) >> 16;   // RNE
    return (uint16_t)r;
}

__device__ __forceinline__ void gld_lds16(const void* g, void* l) {
    __builtin_amdgcn_global_load_lds(
        (const __attribute__((address_space(1))) uint32_t*)g,
        (__attribute__((address_space(3))) uint32_t*)l, 16, 0, 0);
}

// ---- R6-proven pair-batched GEMM phase: M=96 (2 batches x 48) x N=128,
// K=2048, BK=64, depth-2 counted-vmcnt pipeline, T2 slot swizzle.
// 512 threads = 8 waves tiled 2(M) x 4(N). bid: nbp = bid>>4, n0 = (bid&15)*128.
// mode 0: pairsum epilogue -> x (bf16). mode 1: relu(+bias) -> out (f32).
__device__ __forceinline__ void gemm_phase(
    const uint16_t* A, const uint16_t* Bt, const float* bias, void* Cv,
    int mode, uint16_t (*smem)[14336], int t, int bid) {
    float* yt = (float*)&smem[0][0];

    int lane = t & 63, wave = t >> 6;
    int l15 = lane & 15, quad = lane >> 4;
    int wr = wave >> 2, wc = wave & 3;         // wave tile: rows wr*48, cols wc*32
    int nbp = bid >> 4;                        // batch pair
    int n0 = (bid & 15) * 128;
    const uint16_t* Ab = A + (size_t)nbp * 72 * D_DIM;

    // 28 regions of 1KB, r = wave + 8c (waves 0-3: 4 regions, waves 4-7: 3):
    //  r<12: A (g=r>>1 row-group of 96, h=r&1 K-half); junk LDS rows 36-47 /
    //        84-95 read past real rows (in-workspace), outputs discarded.
    //  r>=12: B (rb=r-12).
    const uint16_t* gp[4];
    int loff[4];
    int wslot = (lane & 3) ^ ((lane >> 2) & 3);
#pragma unroll
    for (int c = 0; c < 4; ++c) {
        int r = wave + 8 * c;
        int rr = (r < 28) ? r : 0;
        if (rr < 12) {
            int g = rr >> 1, h = rr & 1;
            int arow = g * 16 + (lane >> 2) - (g >= 3 ? 12 : 0);
            gp[c] = Ab + (size_t)arow * D_DIM + h * 32 + wslot * 8;
            loff[c] = h * 3072 + g * 512;
        } else {
            int rb = rr - 12, g = rb >> 1, h = rb & 1;
            int brow = g * 16 + (lane >> 2);
            gp[c] = Bt + (size_t)(n0 + brow) * D_DIM + h * 32 + wslot * 8;
            loff[c] = 6144 + h * 4096 + g * 512;
        }
    }

    f32x4 acc[3][2] = {};
    int rslot = quad ^ (l15 & 3);   // read-side swizzle: row&3 == l15&3

#define STAGE(kk, bi)                                    \
    {                                                    \
        _Pragma("unroll")                                \
        for (int c = 0; c < 4; ++c)                      \
            if (wave + 8 * c < 28)                       \
                gld_lds16(gp[c] + (kk), &smem[bi][loff[c]]); \
    }
#define WAIT_L()                                                      \
    {                                                                 \
        if (wave < 4) asm volatile("s_waitcnt vmcnt(4)" ::: "memory");\
        else          asm volatile("s_waitcnt vmcnt(3)" ::: "memory");\
    }

    STAGE(0, 0);
    STAGE(64, 1);
    WAIT_L();
    __builtin_amdgcn_s_barrier();

    for (int k = 0; k < 32; ++k) {
        int cur = k & 1;
        const uint16_t* As = &smem[cur][0];
        const uint16_t* Bs = As + 6144;
#pragma unroll
        for (int s = 0; s < 2; ++s) {
            bf16x8 af[3], bfr[2];
#pragma unroll
            for (int i = 0; i < 3; ++i)
                af[i] = *(const bf16x8*)(As + s * 3072 + (wr * 48 + i * 16 + l15) * 32 + rslot * 8);
#pragma unroll
            for (int j = 0; j < 2; ++j)
                bfr[j] = *(const bf16x8*)(Bs + s * 4096 + (wc * 32 + j * 16 + l15) * 32 + rslot * 8);
#pragma unroll
            for (int i = 0; i < 3; ++i)
#pragma unroll
                for (int j = 0; j < 2; ++j)
                    acc[i][j] = __builtin_amdgcn_mfma_f32_16x16x32_bf16(af[i], bfr[j], acc[i][j], 0, 0, 0);
        }
        if (k == 31) break;
        __builtin_amdgcn_s_barrier();              // all waves done reading buf[cur]
        if (k < 30) {
            STAGE((k + 2) * 64, cur);              // refill freed buffer
            WAIT_L();                              // stage k+1 retired; k+2 in flight
        } else {
            asm volatile("s_waitcnt vmcnt(0)" ::: "memory");
        }
        __builtin_amdgcn_s_barrier();              // next buffer ready
    }
#undef STAGE
#undef WAIT_L

    if (mode == 0) {
        uint16_t* X = (uint16_t*)Cv;
        __syncthreads();
#pragma unroll
        for (int i = 0; i < 3; ++i)
#pragma unroll
            for (int j = 0; j < 2; ++j)
#pragma unroll
                for (int r = 0; r < 4; ++r)
                    yt[(wr * 48 + i * 16 + quad * 4 + r) * 132 + wc * 32 + j * 16 + l15] = acc[i][j][r];
        __syncthreads();
        int col = t & 127, sub = t >> 7;
        int b = sub >> 1, half = sub & 1;
        float bv = bias[n0 + col];
        float z[36];
#pragma unroll
        for (int j = 0; j < 36; ++j) z[j] = yt[(b * 48 + j) * 132 + col];
#pragma unroll
        for (int ii = 0; ii < 18; ++ii) {
            int i = half * 18 + ii;
            float zi = z[i] + bv;
            float s = 0.f;
#pragma unroll
            for (int j = 0; j < 36; ++j) s += fmaxf(zi + z[j], 0.f);
            X[(size_t)((nbp * 2 + b) * B_OBJ + i) * D_DIM + n0 + col] = f2bf(s);
        }
    } else {
        float* O = (float*)Cv;
#pragma unroll
        for (int i = 0; i < 3; ++i)
#pragma unroll
            for (int r = 0; r < 4; ++r) {
                int obj = i * 16 + quad * 4 + r;
                if (obj < B_OBJ) {
#pragma unroll
                    for (int j = 0; j < 2; ++j) {
                        int cc = n0 + wc * 32 + j * 16 + l15;
                        O[(size_t)((nbp * 2 + wr) * B_OBJ + obj) * D_DIM + cc] =
                            fmaxf(acc[i][j][r] + bias[cc], 0.f);
                    }
                }
            }
    }
}

// ---- single cooperative kernel: transpose -> qk -> qe*v -> gemm1 -> gemm2 ----
// grid 256 x 512 threads (the gemm geometry); other phases grid-stride onto it.
__global__ __launch_bounds__(512) void fused_all(
    const float* __restrict__ v, const float* __restrict__ q,
    const float* __restrict__ W1, const float* __restrict__ b1,
    const float* __restrict__ W2, const float* __restrict__ b2,
    const float* __restrict__ W3, const float* __restrict__ b3,
    float* __restrict__ out,
    uint16_t* W1t, uint16_t* W2t, uint16_t* W3t,
    uint16_t* u, float* qpart, uint16_t* x) {
    __shared__ __align__(16) uint16_t smem[2][14336];   // 57344 B union
    int t = threadIdx.x;
    int bid = blockIdx.x;
    cg::grid_group grid = cg::this_grid();

    // ---- phase T: transpose + f32->bf16 (2560 virtual 256-thr blocks) ----
    {
        int half = t >> 8, tt = t & 255;
        float (*tile)[65] = (float(*)[65])(&smem[0][0] + half * 8320);  // 64x65 f32 per half
        for (int vb = bid * 2 + half; vb < 2560; vb += 512) {           // 5 iters, uniform
            int gy = vb >> 5, n0 = (vb & 31) * 64;
            const float* W; uint16_t* Wt; int K, k0;
            if (gy < 32)      { W = W1; Wt = W1t; K = 2048; k0 = gy * 64; }
            else if (gy < 64) { W = W2; Wt = W2t; K = 2048; k0 = (gy - 32) * 64; }
            else              { W = W3; Wt = W3t; K = 1024; k0 = (gy - 64) * 64; }
            {
                int r = tt >> 4, c = (tt & 15) * 4;
#pragma unroll
                for (int p = 0; p < 4; ++p)
                    *(float4*)&tile[r + p * 16][c] =
                        *(const float4*)&W[(size_t)(k0 + r + p * 16) * 2048 + n0 + c];
            }
            __syncthreads();
            {
                int n = tt >> 2, kb = (tt & 3) * 16;
#pragma unroll
                for (int g4 = 0; g4 < 4; ++g4) {
                    int k = kb + g4 * 4;
                    ushort4 o;
                    o.x = f2bf(tile[k][n]);     o.y = f2bf(tile[k + 1][n]);
                    o.z = f2bf(tile[k + 2][n]); o.w = f2bf(tile[k + 3][n]);
                    *(ushort4*)&Wt[(size_t)(n0 + n) * K + k0 + k] = o;
                }
            }
            __syncthreads();   // tile reused next iteration
        }
    }
    grid.sync();

    // ---- phase Q: qk split-K GEMM (64 virtual 256-thr blocks on bids 0-31) ----
    {
        int half = t >> 8, tt = t & 255;
        int vb = bid * 2 + half;
        if (vb < 64) {                               // bids 0-31: both halves active
            uint16_t* As = &smem[0][0] + half * 5120;   // [32][32]
            uint16_t* Bs = As + 1024;                   // [128][32]
            int lane = tt & 63, wave = tt >> 6;
            int l15 = lane & 15, quad = lane >> 4;
            int n0 = (vb & 15) * 128;
            int kbase = (vb >> 4) * 256;
            f32x4 acc[2][2] = {};
            int ar = tt >> 3, ac = (tt & 7) * 4;
            int br = tt >> 2, bk = (tt & 3) * 8;
            for (int k0 = 0; k0 < 256; k0 += 32) {
                __syncthreads();
                float4 av = *(const float4*)&q[(size_t)ar * Q_DIM + kbase + k0 + ac];
                ushort4 a4;
                a4.x = f2bf(av.x); a4.y = f2bf(av.y); a4.z = f2bf(av.z); a4.w = f2bf(av.w);
                *(ushort4*)&As[ar * 32 + ac] = a4;
                *(uint4*)&Bs[br * 32 + bk] =
                    *(const uint4*)&W3t[(size_t)(n0 + br) * Q_DIM + kbase + k0 + bk];
                *(uint4*)&Bs[(br + 64) * 32 + bk] =
                    *(const uint4*)&W3t[(size_t)(n0 + br + 64) * Q_DIM + kbase + k0 + bk];
                __syncthreads();
                bf16x8 af[2], bfr[2];
                af[0]  = *(const bf16x8*)&As[l15 * 32 + quad * 8];
                af[1]  = *(const bf16x8*)&As[(16 + l15) * 32 + quad * 8];
                bfr[0] = *(const bf16x8*)&Bs[(wave * 32 + l15) * 32 + quad * 8];
                bfr[1] = *(const bf16x8*)&Bs[(wave * 32 + 16 + l15) * 32 + quad * 8];
#pragma unroll
                for (int i = 0; i < 2; ++i)
#pragma unroll
                    for (int j = 0; j < 2; ++j)
                        acc[i][j] = __builtin_amdgcn_mfma_f32_16x16x32_bf16(af[i], bfr[j], acc[i][j], 0, 0, 0);
            }
            float* dst = qpart + (size_t)(vb >> 4) * 32 * D_DIM;
#pragma unroll
            for (int i = 0; i < 2; ++i)
#pragma unroll
                for (int j = 0; j < 2; ++j) {
                    int n = n0 + wave * 32 + j * 16 + l15;
#pragma unroll
                    for (int r = 0; r < 4; ++r)
                        dst[(size_t)(i * 16 + quad * 4 + r) * D_DIM + n] = acc[i][j][r];
                }
        }
    }
    grid.sync();

    // ---- phase U: qe = relu(sum qpart + b3); u = bf16(v * qe) ----
    {
        int idx = bid * 512 + t;
        if (idx < 16384) {                 // 32 batches x 512 float4-chunks
            int nb = idx >> 9, d4 = idx & 511;
            const float4* p = (const float4*)qpart;
            size_t base = (size_t)nb * 512 + d4;
            float4 s0 = p[base], s1 = p[16384 + base], s2 = p[32768 + base], s3 = p[49152 + base];
            float4 b = ((const float4*)b3)[d4];
            float4 qe;
            qe.x = fmaxf(s0.x + s1.x + s2.x + s3.x + b.x, 0.f);
            qe.y = fmaxf(s0.y + s1.y + s2.y + s3.y + b.y, 0.f);
            qe.z = fmaxf(s0.z + s1.z + s2.z + s3.z + b.z, 0.f);
            qe.w = fmaxf(s0.w + s1.w + s2.w + s3.w + b.w, 0.f);
            const float4* v4 = (const float4*)v;
            ushort4* u4 = (ushort4*)u;
            size_t rb = (size_t)nb * B_OBJ * 512 + d4;
#pragma unroll 4
            for (int i = 0; i < B_OBJ; ++i) {
                float4 vv = v4[rb + (size_t)i * 512];
                ushort4 o;
                o.x = f2bf(vv.x * qe.x);
                o.y = f2bf(vv.y * qe.y);
                o.z = f2bf(vv.z * qe.z);
                o.w = f2bf(vv.w * qe.w);
                u4[rb + (size_t)i * 512] = o;
            }
        }
    }
    grid.sync();

    // ---- phase G1: u @ W1t + pairsum -> x (bf16) ----
    gemm_phase(u, W1t, b1, x, 0, smem, t, bid);
    grid.sync();

    // ---- phase G2: x @ W2t + bias + relu -> out (f32) ----
    gemm_phase(x, W2t, b2, out, 1, smem, t, bid);
}

extern "C" void kernel_launch(void* const* d_in, const int* in_sizes, int n_in,
                              void* d_out, int out_size, void* d_ws, size_t ws_size,
                              hipStream_t stream) {
    const float* v  = (const float*)d_in[0];
    const float* q  = (const float*)d_in[1];
    const float* W1 = (const float*)d_in[2];
    const float* b1 = (const float*)d_in[3];
    const float* W2 = (const float*)d_in[4];
    const float* b2 = (const float*)d_in[5];
    const float* W3 = (const float*)d_in[6];
    const float* b3 = (const float*)d_in[7];
    float* out = (float*)d_out;

    char* ws = (char*)d_ws;
    uint16_t* W1t   = (uint16_t*)(ws + 0);           // 8 MiB
    uint16_t* W2t   = (uint16_t*)(ws + 8388608);     // 8 MiB
    uint16_t* W3t   = (uint16_t*)(ws + 16777216);    // 4 MiB, dead after phase Q
    uint16_t* u     = (uint16_t*)(ws + 16777216);    // 4.5 MiB (overlays dead W3t)
    float*    qpart = (float*)   (ws + 21495808);    // 1 MiB (also pads u over-reads)
    uint16_t* x     = (uint16_t*)(ws + 22806528);    // 4.5 MiB (ends 27525120; ws pads over-reads)

    void* args[] = {
        (void*)&v, (void*)&q, (void*)&W1, (void*)&b1, (void*)&W2, (void*)&b2,
        (void*)&W3, (void*)&b3, (void*)&out, (void*)&W1t, (void*)&W2t,
        (void*)&W3t, (void*)&u, (void*)&qpart, (void*)&x};
    hipLaunchCooperativeKernel((const void*)fused_all, dim3(256), dim3(512),
                               args, 0, stream);
}

// Round 9
// 168.270 us; speedup vs baseline: 1.8166x; 1.8166x over previous
//
#include <hip/hip_runtime.h>
#include <stdint.h>

#define N_BATCH 32
#define B_OBJ   36
#define D_DIM   2048
#define Q_DIM   1024

typedef __bf16 bf16x8 __attribute__((ext_vector_type(8)));
typedef float  f32x4  __attribute__((ext_vector_type(4)));

__device__ __forceinline__ uint16_t f2bf(float f) {
    uint32_t u = __builtin_bit_cast(uint32_t, f);
    uint32_t r = (u + 0x7FFFu + ((u >> 16) & 1u)) >> 16;   // RNE
    return (uint16_t)r;
}

__device__ __forceinline__ void gld_lds16(const void* g, void* l) {
    __builtin_amdgcn_global_load_lds(
        (const __attribute__((address_space(1))) uint32_t*)g,
        (__attribute__((address_space(3))) uint32_t*)l, 16, 0, 0);
}

// ---- transpose + fp32->bf16, 64x64 tiles, vectorized ----
__global__ __launch_bounds__(256) void transpose_all(
    const float* __restrict__ W1, const float* __restrict__ W2,
    const float* __restrict__ W3,
    uint16_t* __restrict__ W1t, uint16_t* __restrict__ W2t,
    uint16_t* __restrict__ W3t) {
    __shared__ float tile[64][65];
    int gy = blockIdx.y;
    const float* W; uint16_t* Wt; int K, k0;
    if (gy < 32)      { W = W1; Wt = W1t; K = 2048; k0 = gy * 64; }
    else if (gy < 64) { W = W2; Wt = W2t; K = 2048; k0 = (gy - 32) * 64; }
    else              { W = W3; Wt = W3t; K = 1024; k0 = (gy - 64) * 64; }
    int n0 = blockIdx.x * 64;
    int t = threadIdx.x;
    {
        int r = t >> 4, c = (t & 15) * 4;
#pragma unroll
        for (int p = 0; p < 4; ++p)
            *(float4*)&tile[r + p * 16][c] =
                *(const float4*)&W[(size_t)(k0 + r + p * 16) * 2048 + n0 + c];
    }
    __syncthreads();
    {
        int n = t >> 2, kb = (t & 3) * 16;
#pragma unroll
        for (int g4 = 0; g4 < 4; ++g4) {
            int k = kb + g4 * 4;
            ushort4 o;
            o.x = f2bf(tile[k][n]);     o.y = f2bf(tile[k + 1][n]);
            o.z = f2bf(tile[k + 2][n]); o.w = f2bf(tile[k + 3][n]);
            *(ushort4*)&Wt[(size_t)(n0 + n) * K + k0 + k] = o;
        }
    }
}

// ---- qe GEMM: qpart[z] = q @ W3 over K-chunk z (M=32, N=2048, split-K=4) ----
__global__ __launch_bounds__(256) void qk_gemm(
    const float* __restrict__ q,
    const uint16_t* __restrict__ W3t,
    float* __restrict__ qpart) {
    __shared__ __align__(16) uint16_t As[32][32];
    __shared__ __align__(16) uint16_t Bs[128][32];
    int t = threadIdx.x, lane = t & 63, wave = t >> 6;
    int l15 = lane & 15, quad = lane >> 4;
    int n0 = blockIdx.x * 128;
    int kbase = blockIdx.y * 256;
    f32x4 acc[2][2] = {};
    int ar = t >> 3, ac = (t & 7) * 4;
    int br = t >> 2, bk = (t & 3) * 8;

    for (int k0 = 0; k0 < 256; k0 += 32) {
        __syncthreads();
        float4 av = *(const float4*)&q[(size_t)ar * Q_DIM + kbase + k0 + ac];
        ushort4 a4;
        a4.x = f2bf(av.x); a4.y = f2bf(av.y); a4.z = f2bf(av.z); a4.w = f2bf(av.w);
        *(ushort4*)&As[ar][ac] = a4;
        *(uint4*)&Bs[br][bk]      = *(const uint4*)&W3t[(size_t)(n0 + br) * Q_DIM + kbase + k0 + bk];
        *(uint4*)&Bs[br + 64][bk] = *(const uint4*)&W3t[(size_t)(n0 + br + 64) * Q_DIM + kbase + k0 + bk];
        __syncthreads();
        bf16x8 af[2], bfr[2];
        af[0]  = *(const bf16x8*)&As[l15][quad * 8];
        af[1]  = *(const bf16x8*)&As[16 + l15][quad * 8];
        bfr[0] = *(const bf16x8*)&Bs[wave * 32 + l15][quad * 8];
        bfr[1] = *(const bf16x8*)&Bs[wave * 32 + 16 + l15][quad * 8];
#pragma unroll
        for (int i = 0; i < 2; ++i)
#pragma unroll
            for (int j = 0; j < 2; ++j)
                acc[i][j] = __builtin_amdgcn_mfma_f32_16x16x32_bf16(af[i], bfr[j], acc[i][j], 0, 0, 0);
    }
    float* dst = qpart + (size_t)blockIdx.y * 32 * D_DIM;
#pragma unroll
    for (int i = 0; i < 2; ++i)
#pragma unroll
        for (int j = 0; j < 2; ++j) {
            int n = n0 + wave * 32 + j * 16 + l15;
#pragma unroll
            for (int r = 0; r < 4; ++r)
                dst[(size_t)(i * 16 + quad * 4 + r) * D_DIM + n] = acc[i][j][r];
        }
}

// ---- fused: qe = relu(sum_z qpart + b3) (in regs); u[n,i,d] = bf16(v*qe) ----
// grid (4, N_BATCH), 128 threads; block owns a 512-float d-chunk of batch nb.
__global__ __launch_bounds__(128) void qe_make_u(
    const float* __restrict__ qpart, const float* __restrict__ b3,
    const float* __restrict__ v, uint16_t* __restrict__ u) {
    int nb = blockIdx.y;
    int d4 = blockIdx.x * 128 + threadIdx.x;          // float4 index in row (512/row)
    const float4* p = (const float4*)qpart;
    size_t base = (size_t)nb * 512 + d4;
    float4 s0 = p[base], s1 = p[16384 + base], s2 = p[32768 + base], s3 = p[49152 + base];
    float4 b = ((const float4*)b3)[d4];
    float4 qe;
    qe.x = fmaxf(s0.x + s1.x + s2.x + s3.x + b.x, 0.f);
    qe.y = fmaxf(s0.y + s1.y + s2.y + s3.y + b.y, 0.f);
    qe.z = fmaxf(s0.z + s1.z + s2.z + s3.z + b.z, 0.f);
    qe.w = fmaxf(s0.w + s1.w + s2.w + s3.w + b.w, 0.f);
    const float4* v4 = (const float4*)v;
    ushort4* u4 = (ushort4*)u;
    size_t rb = (size_t)nb * B_OBJ * 512 + d4;
#pragma unroll 4
    for (int i = 0; i < B_OBJ; ++i) {
        float4 vv = v4[rb + (size_t)i * 512];
        ushort4 o;
        o.x = f2bf(vv.x * qe.x);
        o.y = f2bf(vv.y * qe.y);
        o.z = f2bf(vv.z * qe.z);
        o.w = f2bf(vv.w * qe.w);
        u4[rb + (size_t)i * 512] = o;
    }
}

// ---- pair-batched GEMM: tile M=96 (2 batches x 48) x N=128, K=2048, BK=128 ----
// R6 structure with BK doubled 64->128: 16 K-steps instead of 32 -> half the
// barrier drains; stage k+1's flight time = one compute phase (~1300 cyc),
// now > post-poison L2/HBM latency. Occupancy already 1 block/CU, so the
// 112 KB LDS costs nothing (m132's BK=128 regression was an occupancy cliff).
// 56 staging regions of 1KB/step = exactly 7 per wave (uniform vmcnt(7)).
// Depth-2 counted-vmcnt pipeline, T2 slot swizzle on stage-source + read.
// mode 0: pairsum epilogue -> x (bf16). mode 1: relu(+bias) -> out (f32).
__global__ __launch_bounds__(512) void gemm_batch(
    const uint16_t* __restrict__ A,    // 1152 x 2048 bf16 (32 batches x 36 rows)
    const uint16_t* __restrict__ Bt,   // 2048 x 2048 bf16 (n-major)
    const float* __restrict__ bias,
    void* __restrict__ Cv,
    int mode) {
    // Buffer: As = [4 q][96 rows][32 u16] = 12288 u16 (24 KB),
    //         Bs = [4 q][128][32] = 16384 u16 (32 KB) -> 28672 u16 = 57344 B; x2.
    // Epilogue reuses as yt[96][132] f32 = 50688 B.
    extern __shared__ __align__(16) uint16_t smem[];
    float* yt = (float*)smem;

    int t = threadIdx.x, lane = t & 63, wave = t >> 6;
    int l15 = lane & 15, quad = lane >> 4;
    int wr = wave >> 2, wc = wave & 3;         // wave tile: rows wr*48, cols wc*32
    int nbp = blockIdx.y;                      // batch pair: batches 2*nbp, 2*nbp+1
    int n0 = blockIdx.x * 128;
    const uint16_t* Ab = A + (size_t)nbp * 72 * D_DIM;   // 72 real rows per pair

    // 56 regions of 1KB, region r = wave + 8c (c = 0..6, uniform 7/wave):
    //  r<24:  A: g=r>>2 (row group g*16 of 96), h=r&3 (K-quarter of 128).
    //         LDS rows 0-47 = batch0 (36 real + 12 junk), 48-95 = batch1
    //         (real arow = ldsrow-12; junk rows read in-workspace, discarded).
    //  r>=24: B: rb=r-24: g=rb>>2 (row group of 128), h=rb&3.
    // Region = 16 rows x 32 u16; lane -> row lane>>2, swizzled 16B slot.
    const uint16_t* gp[7];
    int loff[7];
    int wslot = (lane & 3) ^ ((lane >> 2) & 3);
#pragma unroll
    for (int c = 0; c < 7; ++c) {
        int r = wave + 8 * c;
        if (r < 24) {
            int g = r >> 2, h = r & 3;
            int arow = g * 16 + (lane >> 2) - (g >= 3 ? 12 : 0);
            gp[c] = Ab + (size_t)arow * D_DIM + h * 32 + wslot * 8;
            loff[c] = h * 3072 + g * 512;
        } else {
            int rb = r - 24, g = rb >> 2, h = rb & 3;
            int brow = g * 16 + (lane >> 2);
            gp[c] = Bt + (size_t)(n0 + brow) * D_DIM + h * 32 + wslot * 8;
            loff[c] = 12288 + h * 4096 + g * 512;
        }
    }

    f32x4 acc[3][2] = {};
    // read-side swizzled slot: all rows this lane reads have row&3 == l15&3
    int rslot = quad ^ (l15 & 3);

#define STAGE(kk, bi)                                            \
    {                                                            \
        _Pragma("unroll")                                        \
        for (int c = 0; c < 7; ++c)                              \
            gld_lds16(gp[c] + (kk), smem + (bi) * 28672 + loff[c]); \
    }

    // prologue: fill both buffers; wait for stage0 only (stage1's 7 in flight)
    STAGE(0, 0);
    STAGE(128, 1);
    asm volatile("s_waitcnt vmcnt(7)" ::: "memory");
    __builtin_amdgcn_s_barrier();

    for (int k = 0; k < 16; ++k) {
        int cur = k & 1;
        const uint16_t* As = smem + cur * 28672;
        const uint16_t* Bs = As + 12288;
#pragma unroll
        for (int s = 0; s < 4; ++s) {
            bf16x8 af[3], bfr[2];
#pragma unroll
            for (int i = 0; i < 3; ++i)
                af[i] = *(const bf16x8*)(As + s * 3072 + (wr * 48 + i * 16 + l15) * 32 + rslot * 8);
#pragma unroll
            for (int j = 0; j < 2; ++j)
                bfr[j] = *(const bf16x8*)(Bs + s * 4096 + (wc * 32 + j * 16 + l15) * 32 + rslot * 8);
#pragma unroll
            for (int i = 0; i < 3; ++i)
#pragma unroll
                for (int j = 0; j < 2; ++j)
                    acc[i][j] = __builtin_amdgcn_mfma_f32_16x16x32_bf16(af[i], bfr[j], acc[i][j], 0, 0, 0);
        }
        if (k == 15) break;
        __builtin_amdgcn_s_barrier();              // all waves done reading buf[cur]
        if (k < 14) {
            STAGE((k + 2) * 128, cur);             // refill freed buffer
            asm volatile("s_waitcnt vmcnt(7)" ::: "memory");  // stage k+1 retired
        } else {                                   // k == 14: drain stage 15
            asm volatile("s_waitcnt vmcnt(0)" ::: "memory");
        }
        __builtin_amdgcn_s_barrier();              // next buffer ready
    }
#undef STAGE

    if (mode == 0) {
        uint16_t* X = (uint16_t*)Cv;
        __syncthreads();   // all waves done with K-loop before smem reuse as yt
#pragma unroll
        for (int i = 0; i < 3; ++i)
#pragma unroll
            for (int j = 0; j < 2; ++j)
#pragma unroll
                for (int r = 0; r < 4; ++r)
                    yt[(wr * 48 + i * 16 + quad * 4 + r) * 132 + wc * 32 + j * 16 + l15] = acc[i][j][r];
        __syncthreads();
        int col = t & 127, sub = t >> 7;           // sub: 0..3
        int b = sub >> 1, half = sub & 1;          // batch-in-pair, row-half
        float bv = bias[n0 + col];
        float z[36];
#pragma unroll
        for (int j = 0; j < 36; ++j) z[j] = yt[(b * 48 + j) * 132 + col];
#pragma unroll
        for (int ii = 0; ii < 18; ++ii) {
            int i = half * 18 + ii;
            float zi = z[i] + bv;
            float s = 0.f;
#pragma unroll
            for (int j = 0; j < 36; ++j) s += fmaxf(zi + z[j], 0.f);
            X[(size_t)((nbp * 2 + b) * B_OBJ + i) * D_DIM + n0 + col] = f2bf(s);
        }
    } else {
        float* O = (float*)Cv;
#pragma unroll
        for (int i = 0; i < 3; ++i)
#pragma unroll
            for (int r = 0; r < 4; ++r) {
                int obj = i * 16 + quad * 4 + r;   // row within this wave's batch
                if (obj < B_OBJ) {
#pragma unroll
                    for (int j = 0; j < 2; ++j) {
                        int cc = n0 + wc * 32 + j * 16 + l15;
                        O[(size_t)((nbp * 2 + wr) * B_OBJ + obj) * D_DIM + cc] =
                            fmaxf(acc[i][j][r] + bias[cc], 0.f);
                    }
                }
            }
    }
}

extern "C" void kernel_launch(void* const* d_in, const int* in_sizes, int n_in,
                              void* d_out, int out_size, void* d_ws, size_t ws_size,
                              hipStream_t stream) {
    const float* v  = (const float*)d_in[0];
    const float* q  = (const float*)d_in[1];
    const float* W1 = (const float*)d_in[2];
    const float* b1 = (const float*)d_in[3];
    const float* W2 = (const float*)d_in[4];
    const float* b2 = (const float*)d_in[5];
    const float* W3 = (const float*)d_in[6];
    const float* b3 = (const float*)d_in[7];
    float* out = (float*)d_out;

    char* ws = (char*)d_ws;
    uint16_t* W1t   = (uint16_t*)(ws + 0);           // 8 MiB
    uint16_t* W2t   = (uint16_t*)(ws + 8388608);     // 8 MiB
    uint16_t* W3t   = (uint16_t*)(ws + 16777216);    // 4 MiB, dead after qk_gemm
    uint16_t* u     = (uint16_t*)(ws + 16777216);    // 4.5 MiB (overlays dead W3t)
    float*    qpart = (float*)   (ws + 21495808);    // 1 MiB (also pads u over-reads)
    uint16_t* x     = (uint16_t*)(ws + 22806528);    // 4.5 MiB (ends 27525120; ws pads over-reads)

    // allow 114688 B of dynamic LDS for the BK=128 double buffer (capture-safe)
    static bool attr_done = false;
    if (!attr_done) {
        (void)hipFuncSetAttribute((const void*)gemm_batch,
                                  hipFuncAttributeMaxDynamicSharedMemorySize, 114688);
        attr_done = true;
    }

    transpose_all<<<dim3(32, 80), 256, 0, stream>>>(W1, W2, W3, W1t, W2t, W3t);

    qk_gemm<<<dim3(16, 4), 256, 0, stream>>>(q, W3t, qpart);

    qe_make_u<<<dim3(4, N_BATCH), 128, 0, stream>>>(qpart, b3, v, u);

    // GEMM1 + fused pairsum -> x (bf16); 16 batch pairs
    gemm_batch<<<dim3(16, 16), 512, 114688, stream>>>(u, W1t, b1, x, 0);

    // GEMM2 + bias + relu -> out (f32)
    gemm_batch<<<dim3(16, 16), 512, 114688, stream>>>(x, W2t, b2, out, 1);
}